// Round 1
// baseline (16793.394 us; speedup 1.0000x reference)
//
#include <hip/hip_runtime.h>
#include <hip/hip_bf16.h>
#include <math.h>

// Problem constants
#define B_   256
#define M_   6
#define N_   1536      // B*M
#define INC_ 448
#define EMB_ 32
#define D_   512
#define DFF_ 2048
#define OBS_ 20
#define HOR_ 30
#define H_   448

// ---------------------------------------------------------------------------
// Generic tiled fp32 GEMM: C[N,J] = act(A[N,K] @ B[K,J] + colBias[j] + rowMat[n/6, j])
// grid = (J/64, Nrows/64), block = 256. N rows and J cols must be multiples of 64.
// ---------------------------------------------------------------------------
__global__ __launch_bounds__(256) void gemm_k(
    const float* __restrict__ A, int lda,
    const float* __restrict__ Bw, int ldb,
    float* __restrict__ C, int ldc,
    int K,
    const float* __restrict__ colBias,
    const float* __restrict__ rowMat, int ldRm,
    int doRelu)
{
    __shared__ float As[16][68];
    __shared__ float Bs[16][68];
    const int tid = threadIdx.x;
    const int tx = tid & 15;   // j-group
    const int ty = tid >> 4;   // n-group
    const int n0 = blockIdx.y * 64;
    const int j0 = blockIdx.x * 64;
    float acc[4][4] = {};

    const int a_kk  = tid & 15;
    const int a_nn0 = tid >> 4;
    const int b_jj  = tid & 63;
    const int b_kk0 = tid >> 6;

    for (int k0 = 0; k0 < K; k0 += 16) {
#pragma unroll
        for (int i = 0; i < 4; i++) {
            int nn = a_nn0 + 16 * i;
            float v = 0.f;
            if (k0 + a_kk < K) v = A[(size_t)(n0 + nn) * lda + k0 + a_kk];
            As[a_kk][nn] = v;
        }
#pragma unroll
        for (int i = 0; i < 4; i++) {
            int kk = b_kk0 + 4 * i;
            float v = 0.f;
            if (k0 + kk < K) v = Bw[(size_t)(k0 + kk) * ldb + j0 + b_jj];
            Bs[kk][b_jj] = v;
        }
        __syncthreads();
#pragma unroll
        for (int kk = 0; kk < 16; kk++) {
            float4 av = *(const float4*)&As[kk][ty * 4];
            float4 bv = *(const float4*)&Bs[kk][tx * 4];
            float aa[4] = {av.x, av.y, av.z, av.w};
            float bb[4] = {bv.x, bv.y, bv.z, bv.w};
#pragma unroll
            for (int i = 0; i < 4; i++)
#pragma unroll
                for (int j = 0; j < 4; j++)
                    acc[i][j] += aa[i] * bb[j];
        }
        __syncthreads();
    }
#pragma unroll
    for (int i = 0; i < 4; i++) {
        int n = n0 + ty * 4 + i;
        const float* rm = rowMat ? &rowMat[(size_t)(n / 6) * ldRm] : nullptr;
#pragma unroll
        for (int j = 0; j < 4; j++) {
            int jj = j0 + tx * 4 + j;
            float v = acc[i][j];
            if (colBias) v += colBias[jj];
            if (rm)      v += rm[jj];
            if (doRelu)  v = fmaxf(v, 0.f);
            C[(size_t)n * ldc + jj] = v;
        }
    }
}

// ---------------------------------------------------------------------------
// emb_obs[r, e] = relu(obs[r,0]*W_emb[0,e] + obs[r,1]*W_emb[1,e] + b_emb[e]),
// r over 20*256 rows. grid 640 x 256.
// ---------------------------------------------------------------------------
__global__ __launch_bounds__(256) void emb_obs_k(
    const float* __restrict__ obs, const float* __restrict__ Wemb,
    const float* __restrict__ bemb, float* __restrict__ emb_obs)
{
    int tid = blockIdx.x * 256 + threadIdx.x;
    if (tid >= OBS_ * B_ * EMB_) return;
    int r = tid >> 5, e = tid & 31;
    float v = obs[r * 2] * Wemb[e] + obs[r * 2 + 1] * Wemb[32 + e] + bemb[e];
    emb_obs[tid] = fmaxf(v, 0.f);
}

// ---------------------------------------------------------------------------
// Per-step assembly: A1[n, 0:64] = [emb[t-1] (32) | extras (32)],
// small5[n, 0:7] = [last, goal, dist, tcol].  grid 1536 x 64.
// ---------------------------------------------------------------------------
__global__ __launch_bounds__(64) void assemble_k(
    const float* __restrict__ loc, const float* __restrict__ obs,
    const float* __restrict__ dout, const float* __restrict__ emb_obs,
    const float* __restrict__ emb_gen, float* __restrict__ A1,
    float* __restrict__ small5, int s)
{
    int n = blockIdx.x, b = n / 6, m = n % 6, lane = threadIdx.x;
    float g0 = loc[b * 12 + m * 2], g1 = loc[b * 12 + m * 2 + 1];
    float l0, l1;
    if (s == 0) {
        l0 = obs[(19 * B_ + b) * 2];
        l1 = obs[(19 * B_ + b) * 2 + 1];
    } else {
        l0 = dout[(size_t)b * 360 + m * 60 + (s - 1) * 2];
        l1 = dout[(size_t)b * 360 + m * 60 + (s - 1) * 2 + 1];
    }
    float d0 = g0 - l0, d1 = g1 - l1;
    float tc = (float)(OBS_ + s);
    float v;
    if (lane < 32) {
        v = (s == 0) ? emb_obs[((size_t)19 * B_ + b) * 32 + lane]
                     : emb_gen[((size_t)(s - 1) * N_ + n) * 32 + lane];
    } else {
        int c = lane - 32;
        if      (c < 8)  v = (c & 1) ? g1 : g0;
        else if (c < 16) v = (c & 1) ? l1 : l0;
        else if (c < 24) v = (c & 1) ? d1 : d0;
        else             v = tc;
    }
    A1[(size_t)n * 64 + lane] = v;
    if (lane < 7) {
        float v2;
        if      (lane == 0) v2 = l0;
        else if (lane == 1) v2 = l1;
        else if (lane == 2) v2 = g0;
        else if (lane == 3) v2 = g1;
        else if (lane == 4) v2 = d0;
        else if (lane == 5) v2 = d1;
        else                v2 = tc;
        small5[n * 8 + lane] = v2;
    }
}

// ---------------------------------------------------------------------------
// Attention: one block per n (256 thr = 4 waves, each wave 2 heads).
// scores use only the emb-part of K (shared part is softmax-invariant);
// ctx = (sum_l p*emb[l]) @ Wv_emb + v_sh.
// ---------------------------------------------------------------------------
__global__ __launch_bounds__(256) void attn_k(
    const float* __restrict__ qkvsh,   // (N,1536): q = cols 0..511, v_sh = cols 1024..1535
    const float* __restrict__ emb_obs, // (20,256,32)
    const float* __restrict__ emb_gen, // (30,1536,32)
    const float* __restrict__ Wqkv,    // (512,1536)
    float* __restrict__ ctx,           // (N,512)
    int t)
{
    __shared__ float q_s[512];
    __shared__ float emb_s[49 * 33];
    __shared__ float qp_s[4][32];
    __shared__ float ec_s[4][32];
    __shared__ float at_s[4][64];
    const int n = blockIdx.x;
    const int b = n / 6;
    const int tid = threadIdx.x;

    for (int j = tid; j < 512; j += 256) q_s[j] = qkvsh[(size_t)n * 1536 + j];
    const int tot = t * 32;
    for (int idx = tid; idx < tot; idx += 256) {
        int l = idx >> 5, c = idx & 31;
        float v;
        if (l < OBS_) v = emb_obs[((size_t)l * B_ + b) * 32 + c];
        else          v = emb_gen[((size_t)(l - OBS_) * N_ + n) * 32 + c];
        emb_s[l * 33 + c] = v;
    }
    __syncthreads();

    const int w = tid >> 6;
    const int lane = tid & 63;
    for (int hh = 0; hh < 2; hh++) {
        const int h = w * 2 + hh;
        // qproj[c] = sum_d Wk[c, h*64+d] * q[h*64+d]
        const float qv = q_s[h * 64 + lane];
        for (int c = 0; c < 32; c++) {
            float p = Wqkv[(size_t)c * 1536 + 512 + h * 64 + lane] * qv;
#pragma unroll
            for (int o = 32; o > 0; o >>= 1) p += __shfl_xor(p, o, 64);
            if (lane == 0) qp_s[w][c] = p;
        }
        __syncthreads();
        // scores + online softmax (lane = frame l)
        float sc = -INFINITY;
        if (lane < t) {
            float sacc = 0.f;
            const float* er = &emb_s[lane * 33];
#pragma unroll 8
            for (int c = 0; c < 32; c++) sacc += er[c] * qp_s[w][c];
            sc = sacc * 0.125f;
        }
        float mx = sc;
#pragma unroll
        for (int o = 32; o > 0; o >>= 1) mx = fmaxf(mx, __shfl_xor(mx, o, 64));
        float e = (lane < t) ? __expf(sc - mx) : 0.f;
        float sm = e;
#pragma unroll
        for (int o = 32; o > 0; o >>= 1) sm += __shfl_xor(sm, o, 64);
        at_s[w][lane] = e / sm;
        __syncthreads();
        // embctx[c] = sum_l p_l * emb[l][c]
        if (lane < 32) {
            float ec = 0.f;
            for (int l = 0; l < t; l++) ec += at_s[w][l] * emb_s[l * 33 + lane];
            ec_s[w][lane] = ec;
        }
        __syncthreads();
        // ctx[h*64+d] = embctx @ Wv_emb + v_sh
        float cv = qkvsh[(size_t)n * 1536 + 1024 + h * 64 + lane];
#pragma unroll 8
        for (int c = 0; c < 32; c++)
            cv += ec_s[w][c] * Wqkv[(size_t)c * 1536 + 1024 + h * 64 + lane];
        ctx[(size_t)n * 512 + h * 64 + lane] = cv;
        __syncthreads();
    }
}

// ---------------------------------------------------------------------------
// LN1: h1 = LN(x_last + a), x_last = [A1[n,0:64] | feat[b,0:448]]. grid 1536 x 256.
// ---------------------------------------------------------------------------
__global__ __launch_bounds__(256) void ln1_k(
    const float* __restrict__ a, const float* __restrict__ A1,
    const float* __restrict__ feat, const float* __restrict__ g,
    const float* __restrict__ bt, float* __restrict__ h1)
{
    __shared__ float red[8];
    const int n = blockIdx.x, b = n / 6, tid = threadIdx.x;
    float r[2]; float s = 0.f, sq = 0.f;
#pragma unroll
    for (int i = 0; i < 2; i++) {
        int j = tid + i * 256;
        float x = (j < 64) ? A1[(size_t)n * 64 + j] : feat[(size_t)b * 448 + (j - 64)];
        float v = a[(size_t)n * 512 + j] + x;
        r[i] = v; s += v; sq += v * v;
    }
#pragma unroll
    for (int o = 32; o > 0; o >>= 1) { s += __shfl_xor(s, o, 64); sq += __shfl_xor(sq, o, 64); }
    int w = tid >> 6, lane = tid & 63;
    if (lane == 0) { red[w] = s; red[4 + w] = sq; }
    __syncthreads();
    s  = red[0] + red[1] + red[2] + red[3];
    sq = red[4] + red[5] + red[6] + red[7];
    float mu = s * (1.f / 512.f);
    float var = sq * (1.f / 512.f) - mu * mu;
    float rs = rsqrtf(var + 1e-5f);
#pragma unroll
    for (int i = 0; i < 2; i++) {
        int j = tid + i * 256;
        h1[(size_t)n * 512 + j] = (r[i] - mu) * rs * g[j] + bt[j];
    }
}

// ---------------------------------------------------------------------------
// LN2: h2 = LN(h1 + ff) -> h2p[n,0:512]; append small5 -> h2p[n,512:519]. ld=520.
// ---------------------------------------------------------------------------
__global__ __launch_bounds__(256) void ln2_k(
    const float* __restrict__ h1, const float* __restrict__ ff,
    const float* __restrict__ g, const float* __restrict__ bt,
    const float* __restrict__ small5, float* __restrict__ h2p)
{
    __shared__ float red[8];
    const int n = blockIdx.x, tid = threadIdx.x;
    float r[2]; float s = 0.f, sq = 0.f;
#pragma unroll
    for (int i = 0; i < 2; i++) {
        int j = tid + i * 256;
        float v = h1[(size_t)n * 512 + j] + ff[(size_t)n * 512 + j];
        r[i] = v; s += v; sq += v * v;
    }
#pragma unroll
    for (int o = 32; o > 0; o >>= 1) { s += __shfl_xor(s, o, 64); sq += __shfl_xor(sq, o, 64); }
    int w = tid >> 6, lane = tid & 63;
    if (lane == 0) { red[w] = s; red[4 + w] = sq; }
    __syncthreads();
    s  = red[0] + red[1] + red[2] + red[3];
    sq = red[4] + red[5] + red[6] + red[7];
    float mu = s * (1.f / 512.f);
    float var = sq * (1.f / 512.f) - mu * mu;
    float rs = rsqrtf(var + 1e-5f);
#pragma unroll
    for (int i = 0; i < 2; i++) {
        int j = tid + i * 256;
        h2p[(size_t)n * 520 + j] = (r[i] - mu) * rs * g[j] + bt[j];
    }
    if (tid < 7) h2p[(size_t)n * 520 + 512 + tid] = small5[n * 8 + tid];
}

// ---------------------------------------------------------------------------
// finish: out = fusv @ W_out + b_out -> d_out; emb_gen[s] = relu(out @ W_emb + b_emb).
// One wave per n; block 256 = 4 n.  grid 384.
// ---------------------------------------------------------------------------
__global__ __launch_bounds__(256) void finish_k(
    const float* __restrict__ fusv, const float* __restrict__ Wout,
    const float* __restrict__ bout, const float* __restrict__ Wemb,
    const float* __restrict__ bemb, float* __restrict__ dout,
    float* __restrict__ emb_gen, int s)
{
    const int w = threadIdx.x >> 6, lane = threadIdx.x & 63;
    const int n = blockIdx.x * 4 + w;
    float o0 = 0.f, o1 = 0.f;
    for (int k = lane; k < 448; k += 64) {
        float f = fusv[(size_t)n * 448 + k];
        o0 += f * Wout[k * 2];
        o1 += f * Wout[k * 2 + 1];
    }
#pragma unroll
    for (int o = 32; o > 0; o >>= 1) { o0 += __shfl_xor(o0, o, 64); o1 += __shfl_xor(o1, o, 64); }
    o0 += bout[0]; o1 += bout[1];
    const int b = n / 6, m = n % 6;
    if (lane == 0) {
        dout[(size_t)b * 360 + m * 60 + s * 2]     = o0;
        dout[(size_t)b * 360 + m * 60 + s * 2 + 1] = o1;
    }
    if (lane < 32) {
        float v = o0 * Wemb[lane] + o1 * Wemb[32 + lane] + bemb[lane];
        emb_gen[((size_t)s * N_ + n) * 32 + lane] = fmaxf(v, 0.f);
    }
}

// ---------------------------------------------------------------------------
extern "C" void kernel_launch(void* const* d_in, const int* in_sizes, int n_in,
                              void* d_out_, int out_size, void* d_ws, size_t ws_size,
                              hipStream_t stream) {
    (void)in_sizes; (void)n_in; (void)out_size; (void)ws_size;
    const float* feat  = (const float*)d_in[0];   // (B,1,448) == (B,448)
    const float* loc   = (const float*)d_in[1];   // (B,6,2)
    const float* obs   = (const float*)d_in[2];   // (20,B,2)
    const float* W_emb = (const float*)d_in[3];
    const float* b_emb = (const float*)d_in[4];
    const float* W_qkv = (const float*)d_in[5];   // (512,1536)
    const float* b_qkv = (const float*)d_in[6];
    const float* W_o   = (const float*)d_in[7];   // (512,512)
    const float* b_o   = (const float*)d_in[8];
    const float* W_ff1 = (const float*)d_in[9];   // (512,2048)
    const float* b_ff1 = (const float*)d_in[10];
    const float* W_ff2 = (const float*)d_in[11];  // (2048,512)
    const float* b_ff2 = (const float*)d_in[12];
    const float* ln1_g = (const float*)d_in[13];
    const float* ln1_b = (const float*)d_in[14];
    const float* ln2_g = (const float*)d_in[15];
    const float* ln2_b = (const float*)d_in[16];
    const float* W_fus = (const float*)d_in[17];  // (967,448)
    const float* b_fus = (const float*)d_in[18];
    const float* W_out = (const float*)d_in[19];  // (448,2)
    const float* b_out = (const float*)d_in[20];
    float* dout = (float*)d_out_;

    float* ws = (float*)d_ws;
    float* feat_qkv = ws;  ws += B_ * 1536;       // feat @ W_qkv[64:512] + b_qkv
    float* feat_fus = ws;  ws += B_ * 448;        // feat @ W_fus[519:967] + b_fus
    float* emb_obs  = ws;  ws += OBS_ * B_ * 32;
    float* emb_gen  = ws;  ws += HOR_ * N_ * 32;
    float* A1       = ws;  ws += N_ * 64;
    float* small5   = ws;  ws += N_ * 8;
    float* bufQ     = ws;  ws += N_ * 1536;       // qkvsh -> a -> ff
    float* bufC     = ws;  ws += N_ * 512;        // ctx -> h1
    float* f1       = ws;  ws += N_ * 2048;       // ff1 out -> fusv
    float* h2p      = ws;  ws += N_ * 520;
    float* fusv     = f1;

    // ---- precompute (once per launch) ----
    emb_obs_k<<<dim3(640), dim3(256), 0, stream>>>(obs, W_emb, b_emb, emb_obs);
    gemm_k<<<dim3(24, 4), dim3(256), 0, stream>>>(feat, 448, W_qkv + 64 * 1536, 1536,
        feat_qkv, 1536, 448, b_qkv, nullptr, 0, 0);
    gemm_k<<<dim3(7, 4), dim3(256), 0, stream>>>(feat, 448, W_fus + 519 * 448, 448,
        feat_fus, 448, 448, b_fus, nullptr, 0, 0);

    // ---- 30 sequential decode steps ----
    for (int s = 0; s < HOR_; s++) {
        assemble_k<<<dim3(N_), dim3(64), 0, stream>>>(loc, obs, dout, emb_obs, emb_gen, A1, small5, s);
        // qkvsh = [emb|extras] @ W_qkv[0:64] + feat_qkv[b]   (q cols 0:512, v_sh cols 1024:1536)
        gemm_k<<<dim3(24, 24), dim3(256), 0, stream>>>(A1, 64, W_qkv, 1536,
            bufQ, 1536, 64, nullptr, feat_qkv, 1536, 0);
        attn_k<<<dim3(N_), dim3(256), 0, stream>>>(bufQ, emb_obs, emb_gen, W_qkv, bufC, OBS_ + s);
        // a = ctx @ W_o + b_o
        gemm_k<<<dim3(8, 24), dim3(256), 0, stream>>>(bufC, 512, W_o, 512,
            bufQ, 512, 512, b_o, nullptr, 0, 0);
        ln1_k<<<dim3(N_), dim3(256), 0, stream>>>(bufQ, A1, feat, ln1_g, ln1_b, bufC);
        // f1 = relu(h1 @ W_ff1 + b_ff1)
        gemm_k<<<dim3(32, 24), dim3(256), 0, stream>>>(bufC, 512, W_ff1, 2048,
            f1, 2048, 512, b_ff1, nullptr, 0, 1);
        // ff = f1 @ W_ff2 + b_ff2
        gemm_k<<<dim3(8, 24), dim3(256), 0, stream>>>(f1, 2048, W_ff2, 512,
            bufQ, 512, 2048, b_ff2, nullptr, 0, 0);
        ln2_k<<<dim3(N_), dim3(256), 0, stream>>>(bufC, bufQ, ln2_g, ln2_b, small5, h2p);
        // fusv = [h2|small5] @ W_fus[0:519] + feat_fus[b]
        gemm_k<<<dim3(7, 24), dim3(256), 0, stream>>>(h2p, 520, W_fus, 448,
            fusv, 448, 519, nullptr, feat_fus, 448, 0);
        finish_k<<<dim3(384), dim3(256), 0, stream>>>(fusv, W_out, b_out, W_emb, b_emb, dout, emb_gen, s);
    }
}

// Round 3
// 3576.909 us; speedup vs baseline: 4.6949x; 4.6949x over previous
//
#include <hip/hip_runtime.h>
#include <math.h>

#define B_   256
#define N_   1536
#define OBS_ 20
#define HOR_ 30

typedef __bf16 bf16;
typedef bf16  bf16x8 __attribute__((ext_vector_type(8)));
typedef float f32x4  __attribute__((ext_vector_type(4)));

// ---------------------------------------------------------------------------
// fp32 tiled GEMM (prologue only): C = A@B + colBias, optional bf16 copy.
// grid (J/64, rows/64), block 256.
// ---------------------------------------------------------------------------
__global__ __launch_bounds__(256) void gemm_k(
    const float* __restrict__ A, int lda,
    const float* __restrict__ Bw, int ldb,
    float* __restrict__ C, bf16* __restrict__ Cb, int ldc,
    int K, const float* __restrict__ colBias)
{
    __shared__ float As[16][68];
    __shared__ float Bs[16][68];
    const int tid = threadIdx.x;
    const int tx = tid & 15, ty = tid >> 4;
    const int n0 = blockIdx.y * 64, j0 = blockIdx.x * 64;
    float acc[4][4] = {};
    const int a_kk = tid & 15, a_nn0 = tid >> 4;
    const int b_jj = tid & 63, b_kk0 = tid >> 6;
    for (int k0 = 0; k0 < K; k0 += 16) {
#pragma unroll
        for (int i = 0; i < 4; i++) {
            int nn = a_nn0 + 16 * i;
            As[a_kk][nn] = (k0 + a_kk < K) ? A[(size_t)(n0 + nn) * lda + k0 + a_kk] : 0.f;
        }
#pragma unroll
        for (int i = 0; i < 4; i++) {
            int kk = b_kk0 + 4 * i;
            Bs[kk][b_jj] = (k0 + kk < K) ? Bw[(size_t)(k0 + kk) * ldb + j0 + b_jj] : 0.f;
        }
        __syncthreads();
#pragma unroll
        for (int kk = 0; kk < 16; kk++) {
            float4 av = *(const float4*)&As[kk][ty * 4];
            float4 bv = *(const float4*)&Bs[kk][tx * 4];
            float aa[4] = {av.x, av.y, av.z, av.w};
            float bb[4] = {bv.x, bv.y, bv.z, bv.w};
#pragma unroll
            for (int i = 0; i < 4; i++)
#pragma unroll
                for (int j = 0; j < 4; j++) acc[i][j] += aa[i] * bb[j];
        }
        __syncthreads();
    }
#pragma unroll
    for (int i = 0; i < 4; i++) {
        int n = n0 + ty * 4 + i;
#pragma unroll
        for (int j = 0; j < 4; j++) {
            int jj = j0 + tx * 4 + j;
            float v = acc[i][j];
            if (colBias) v += colBias[jj];
            if (C)  C[(size_t)n * ldc + jj] = v;
            if (Cb) Cb[(size_t)n * ldc + jj] = (bf16)v;
        }
    }
}

// ---------------------------------------------------------------------------
// bf16 MFMA GEMM: C[N,J] = act(A@B + colBias + rowMat[n/6]).
// grid (J/64, N/64), block 256 (4 waves; wave w = 16-row group).
// LDS is MFMA-fragment-ordered: each lane reads its frag as one ds_read_b128.
// ---------------------------------------------------------------------------
__global__ __launch_bounds__(256) void mgemm_k(
    const bf16* __restrict__ A, int lda,
    const bf16* __restrict__ Bw, int ldb,
    int K,
    float* __restrict__ C, bf16* __restrict__ Cb, int ldc,
    const float* __restrict__ colBias,
    const float* __restrict__ rowMat, int ldRm,
    int doRelu)
{
    __shared__ bf16 As[64 * 32];
    __shared__ bf16 Bs[32 * 64];
    const int tid = threadIdx.x;
    const int n0 = blockIdx.y * 64;
    const int j0 = blockIdx.x * 64;
    const int w = tid >> 6;
    const int lane = tid & 63;
    const int quad = lane >> 4;
    const int m15 = lane & 15;
    const int slot = quad * 16 + m15;

    const int am  = tid >> 2;   // A row 0..63
    const int akq = tid & 3;    // A k-octet
    const int bj  = tid & 63;   // B col 0..63
    const int bkq = tid >> 6;   // B k-octet

    f32x4 acc[4] = {};
    for (int k0 = 0; k0 < K; k0 += 32) {
        bf16x8 av = *(const bf16x8*)&A[(size_t)(n0 + am) * lda + k0 + akq * 8];
        bf16x8 bv;
#pragma unroll
        for (int i = 0; i < 8; i++)
            bv[i] = Bw[(size_t)(k0 + bkq * 8 + i) * ldb + j0 + bj];
        __syncthreads();
        *(bf16x8*)&As[((am >> 4) * 64 + akq * 16 + (am & 15)) * 8] = av;
        *(bf16x8*)&Bs[((bj >> 4) * 64 + bkq * 16 + (bj & 15)) * 8] = bv;
        __syncthreads();
        bf16x8 af = *(const bf16x8*)&As[(w * 64 + slot) * 8];
#pragma unroll
        for (int ng = 0; ng < 4; ng++) {
            bf16x8 bfr = *(const bf16x8*)&Bs[(ng * 64 + slot) * 8];
            acc[ng] = __builtin_amdgcn_mfma_f32_16x16x32_bf16(af, bfr, acc[ng], 0, 0, 0);
        }
    }
#pragma unroll
    for (int ng = 0; ng < 4; ng++) {
#pragma unroll
        for (int r = 0; r < 4; r++) {
            int n = n0 + w * 16 + quad * 4 + r;    // C/D: row=(lane>>4)*4+reg
            int j = j0 + ng * 16 + m15;            //       col=lane&15
            float v = acc[ng][r];
            if (colBias) v += colBias[j];
            if (rowMat)  v += rowMat[(size_t)(n / 6) * ldRm + j];
            if (doRelu)  v = fmaxf(v, 0.f);
            if (C)  C[(size_t)n * ldc + j] = v;
            if (Cb) Cb[(size_t)n * ldc + j] = (bf16)v;
        }
    }
}

// ---------------------------------------------------------------------------
__global__ __launch_bounds__(256) void emb_obs_k(
    const float* __restrict__ obs, const float* __restrict__ Wemb,
    const float* __restrict__ bemb, float* __restrict__ emb_obs)
{
    int tid = blockIdx.x * 256 + threadIdx.x;
    if (tid >= OBS_ * B_ * 32) return;
    int r = tid >> 5, e = tid & 31;
    float v = obs[r * 2] * Wemb[e] + obs[r * 2 + 1] * Wemb[32 + e] + bemb[e];
    emb_obs[tid] = fmaxf(v, 0.f);
}

// Weff[r, h*32+c] = sum_d Wqkv[r, h*64+d] * Wqkv[c, 512+h*64+d]; r=512 row = bias_qp.
__global__ __launch_bounds__(256) void weff_k(
    const float* __restrict__ Wqkv, const float* __restrict__ bqkv,
    float* __restrict__ Weff)
{
    __shared__ float qrow[512];
    const int r = blockIdx.x;   // 0..512
    const int t = threadIdx.x;
    for (int j = t; j < 512; j += 256)
        qrow[j] = (r < 512) ? Wqkv[(size_t)r * 1536 + j] : bqkv[j];
    __syncthreads();
    const int h = t >> 5, c = t & 31;
    float acc = 0.f;
#pragma unroll 8
    for (int d = 0; d < 64; d++)
        acc += qrow[h * 64 + d] * Wqkv[(size_t)c * 1536 + 512 + h * 64 + d];
    Weff[(size_t)r * 256 + t] = acc;
}

// WovCat[h*32+c, j] = sum_d Wqkv[c, 1024+h*64+d] * W_o[h*64+d, j]  (rows 0..255, bf16)
__global__ __launch_bounds__(256) void wov_k(
    const float* __restrict__ Wqkv, const float* __restrict__ Wo,
    bf16* __restrict__ WovCat)
{
    __shared__ float vrow[64];
    const int row = blockIdx.x;  // 0..255
    const int h = row >> 5, c = row & 31;
    const int t = threadIdx.x;
    if (t < 64) vrow[t] = Wqkv[(size_t)c * 1536 + 1024 + h * 64 + t];
    __syncthreads();
    for (int j = t; j < 512; j += 256) {
        float acc = 0.f;
#pragma unroll 8
        for (int d = 0; d < 64; d++)
            acc += vrow[d] * Wo[(size_t)(h * 64 + d) * 512 + j];
        WovCat[(size_t)row * 512 + j] = (bf16)acc;
    }
}

// fp32 -> bf16 with zero row padding
__global__ void convpad_k(const float* __restrict__ src, bf16* __restrict__ dst,
                          int rows, int cols, int srcRows)
{
    int i = blockIdx.x * 256 + threadIdx.x;
    if (i >= rows * cols) return;
    int r = i / cols;
    dst[i] = (bf16)((r < srcRows) ? src[i] : 0.f);
}

// ---------------------------------------------------------------------------
// Attention: scores = 0.125 * qp . emb[l]; ec written bf16 into ecA1b[:,0:256].
// grid N, block 256 (4 waves x 2 heads).
// ---------------------------------------------------------------------------
__global__ __launch_bounds__(256) void attn_k(
    const float* __restrict__ qp, const float* __restrict__ emb_obs,
    const float* __restrict__ emb_gen, bf16* __restrict__ ecA1b, int t)
{
    __shared__ float qp_s[256];
    __shared__ float emb_s[50 * 33];
    __shared__ float at_s[4][64];
    const int n = blockIdx.x, b = n / 6, tid = threadIdx.x;
    qp_s[tid] = qp[(size_t)n * 256 + tid];
    for (int idx = tid; idx < t * 32; idx += 256) {
        int l = idx >> 5, c = idx & 31;
        emb_s[l * 33 + c] = (l < OBS_) ? emb_obs[((size_t)l * B_ + b) * 32 + c]
                                       : emb_gen[((size_t)(l - OBS_) * N_ + n) * 32 + c];
    }
    __syncthreads();
    const int w = tid >> 6, lane = tid & 63;
#pragma unroll
    for (int hh = 0; hh < 2; hh++) {
        const int h = w * 2 + hh;
        float sc = -1e30f;
        if (lane < t) {
            float s_ = 0.f;
#pragma unroll 8
            for (int c = 0; c < 32; c++) s_ += emb_s[lane * 33 + c] * qp_s[h * 32 + c];
            sc = s_ * 0.125f;
        }
        float mx = sc;
#pragma unroll
        for (int o = 32; o > 0; o >>= 1) mx = fmaxf(mx, __shfl_xor(mx, o, 64));
        float e = (lane < t) ? __expf(sc - mx) : 0.f;
        float sm = e;
#pragma unroll
        for (int o = 32; o > 0; o >>= 1) sm += __shfl_xor(sm, o, 64);
        at_s[w][lane] = e / sm;   // wave-local use only
        if (lane < 32) {
            float ec = 0.f;
            for (int l = 0; l < t; l++) ec += at_s[w][l] * emb_s[l * 33 + lane];
            ecA1b[(size_t)n * 288 + h * 32 + lane] = (bf16)ec;
        }
    }
}

// ---------------------------------------------------------------------------
// LN1: h1 = LN([A1f|feat] + a) -> h1f fp32 + h1b bf16. grid N x 256.
// ---------------------------------------------------------------------------
__global__ __launch_bounds__(256) void ln1_k(
    const float* __restrict__ a, const float* __restrict__ A1f,
    const float* __restrict__ feat, const float* __restrict__ g,
    const float* __restrict__ bt, float* __restrict__ h1f, bf16* __restrict__ h1b)
{
    __shared__ float red[8];
    const int n = blockIdx.x, b = n / 6, tid = threadIdx.x;
    float r[2]; float s = 0.f, sq = 0.f;
#pragma unroll
    for (int i = 0; i < 2; i++) {
        int j = tid + i * 256;
        float x = (j < 64) ? A1f[(size_t)n * 64 + j] : feat[(size_t)b * 448 + (j - 64)];
        float v = a[(size_t)n * 512 + j] + x;
        r[i] = v; s += v; sq += v * v;
    }
#pragma unroll
    for (int o = 32; o > 0; o >>= 1) { s += __shfl_xor(s, o, 64); sq += __shfl_xor(sq, o, 64); }
    int w = tid >> 6, lane = tid & 63;
    if (lane == 0) { red[w] = s; red[4 + w] = sq; }
    __syncthreads();
    s  = red[0] + red[1] + red[2] + red[3];
    sq = red[4] + red[5] + red[6] + red[7];
    float mu = s * (1.f / 512.f);
    float var = sq * (1.f / 512.f) - mu * mu;
    float rs = rsqrtf(var + 1e-5f);
#pragma unroll
    for (int i = 0; i < 2; i++) {
        int j = tid + i * 256;
        float v = (r[i] - mu) * rs * g[j] + bt[j];
        h1f[(size_t)n * 512 + j] = v;
        h1b[(size_t)n * 512 + j] = (bf16)v;
    }
}

// ---------------------------------------------------------------------------
// LN2: h2p = [LN(h1+ff) | small5 | zeros] as bf16, ld 544. grid N x 256.
// ---------------------------------------------------------------------------
__global__ __launch_bounds__(256) void ln2_k(
    const float* __restrict__ h1, const float* __restrict__ ff,
    const float* __restrict__ g, const float* __restrict__ bt,
    const float* __restrict__ small5, bf16* __restrict__ h2p)
{
    __shared__ float red[8];
    const int n = blockIdx.x, tid = threadIdx.x;
    float r[2]; float s = 0.f, sq = 0.f;
#pragma unroll
    for (int i = 0; i < 2; i++) {
        int j = tid + i * 256;
        float v = h1[(size_t)n * 512 + j] + ff[(size_t)n * 512 + j];
        r[i] = v; s += v; sq += v * v;
    }
#pragma unroll
    for (int o = 32; o > 0; o >>= 1) { s += __shfl_xor(s, o, 64); sq += __shfl_xor(sq, o, 64); }
    int w = tid >> 6, lane = tid & 63;
    if (lane == 0) { red[w] = s; red[4 + w] = sq; }
    __syncthreads();
    s  = red[0] + red[1] + red[2] + red[3];
    sq = red[4] + red[5] + red[6] + red[7];
    float mu = s * (1.f / 512.f);
    float var = sq * (1.f / 512.f) - mu * mu;
    float rs = rsqrtf(var + 1e-5f);
#pragma unroll
    for (int i = 0; i < 2; i++) {
        int j = tid + i * 256;
        h2p[(size_t)n * 544 + j] = (bf16)((r[i] - mu) * rs * g[j] + bt[j]);
    }
    if (tid < 7)  h2p[(size_t)n * 544 + 512 + tid] = (bf16)small5[n * 8 + tid];
    if (tid < 25) h2p[(size_t)n * 544 + 519 + tid] = (bf16)0.f;
}

// ---------------------------------------------------------------------------
// Next-state producer (shared logic)
// ---------------------------------------------------------------------------
__device__ __forceinline__ void next_state(
    int n, int b, int t, float o0, float o1, float g0, float g1, float tc,
    const float* Wemb, const float* bemb, const float* Weff, const float* featqp,
    float* emb_dst, float* A1f, bf16* ecA1b, float* small5, float* qp, float* A1s)
{
    float d0 = g0 - o0, d1 = g1 - o1;
    if (t < 32) {
        float e = fmaxf(o0 * Wemb[t] + o1 * Wemb[32 + t] + bemb[t], 0.f);
        if (emb_dst) emb_dst[t] = e;
        A1s[t] = e;
    } else if (t < 64) {
        int c = t - 32;
        float v;
        if      (c < 8)  v = (c & 1) ? g1 : g0;
        else if (c < 16) v = (c & 1) ? o1 : o0;
        else if (c < 24) v = (c & 1) ? d1 : d0;
        else             v = tc;
        A1s[t] = v;
    }
    if (t < 7) {
        float v2 = (t==0)?o0:(t==1)?o1:(t==2)?g0:(t==3)?g1:(t==4)?d0:(t==5)?d1:tc;
        small5[n * 8 + t] = v2;
    }
    __syncthreads();
    if (t < 64) {
        A1f[(size_t)n * 64 + t] = A1s[t];
        if (t >= 32) ecA1b[(size_t)n * 288 + 256 + (t - 32)] = (bf16)A1s[t];
    }
    float acc = featqp[(size_t)b * 256 + t];
#pragma unroll 8
    for (int k = 0; k < 64; k++) acc += A1s[k] * Weff[k * 256 + t];
    qp[(size_t)n * 256 + t] = acc;
}

__global__ __launch_bounds__(256) void init_k(
    const float* __restrict__ obs, const float* __restrict__ emb_obs,
    const float* __restrict__ loc, const float* __restrict__ Weff,
    const float* __restrict__ featqp,
    float* __restrict__ A1f, bf16* __restrict__ ecA1b,
    float* __restrict__ small5, float* __restrict__ qp)
{
    __shared__ float A1s[64];
    const int n = blockIdx.x, b = n / 6, m = n % 6, t = threadIdx.x;
    float o0 = obs[(19 * B_ + b) * 2], o1 = obs[(19 * B_ + b) * 2 + 1];
    float g0 = loc[b * 12 + m * 2], g1 = loc[b * 12 + m * 2 + 1];
    if (t < 32) {  // emb of last obs frame comes from emb_obs, not W_emb(out)
        A1s[t] = emb_obs[((size_t)19 * B_ + b) * 32 + t];
    } else if (t < 64) {
        int c = t - 32; float d0 = g0 - o0, d1 = g1 - o1; float tc = 20.f;
        float v;
        if      (c < 8)  v = (c & 1) ? g1 : g0;
        else if (c < 16) v = (c & 1) ? o1 : o0;
        else if (c < 24) v = (c & 1) ? d1 : d0;
        else             v = tc;
        A1s[t] = v;
    }
    if (t < 7) {
        float d0 = g0 - o0, d1 = g1 - o1; float tc = 20.f;
        float v2 = (t==0)?o0:(t==1)?o1:(t==2)?g0:(t==3)?g1:(t==4)?d0:(t==5)?d1:tc;
        small5[n * 8 + t] = v2;
    }
    __syncthreads();
    if (t < 64) {
        A1f[(size_t)n * 64 + t] = A1s[t];
        if (t >= 32) ecA1b[(size_t)n * 288 + 256 + (t - 32)] = (bf16)A1s[t];
    }
    float acc = featqp[(size_t)b * 256 + t];
#pragma unroll 8
    for (int k = 0; k < 64; k++) acc += A1s[k] * Weff[k * 256 + t];
    qp[(size_t)n * 256 + t] = acc;
}

// ---------------------------------------------------------------------------
// finish: out = fusv@W_out + b_out -> dout; then produce step s+1 state.
// grid N, block 256.  FIX(R2->R3): each thread accumulates fus elements
// t AND t+256 (448 total) — R2 only summed the first 256.
// ---------------------------------------------------------------------------
__global__ __launch_bounds__(256) void finish_k(
    const float* __restrict__ fusv, const float* __restrict__ Wout,
    const float* __restrict__ bout, const float* __restrict__ Wemb,
    const float* __restrict__ bemb, const float* __restrict__ loc,
    const float* __restrict__ Weff, const float* __restrict__ featqp,
    float* __restrict__ dout, float* __restrict__ emb_gen,
    float* __restrict__ A1f, bf16* __restrict__ ecA1b,
    float* __restrict__ small5, float* __restrict__ qp, int s)
{
    __shared__ float red[8];
    __shared__ float osh[2];
    __shared__ float A1s[64];
    const int n = blockIdx.x, b = n / 6, m = n % 6, t = threadIdx.x;
    float f0 = fusv[(size_t)n * 448 + t];
    float p0 = f0 * Wout[t * 2];
    float p1 = f0 * Wout[t * 2 + 1];
    if (t < 192) {
        float f1 = fusv[(size_t)n * 448 + 256 + t];
        p0 += f1 * Wout[(256 + t) * 2];
        p1 += f1 * Wout[(256 + t) * 2 + 1];
    }
#pragma unroll
    for (int o = 32; o > 0; o >>= 1) { p0 += __shfl_xor(p0, o, 64); p1 += __shfl_xor(p1, o, 64); }
    int w = t >> 6, lane = t & 63;
    if (lane == 0) { red[w] = p0; red[4 + w] = p1; }
    __syncthreads();
    if (t == 0) {
        float o0 = red[0] + red[1] + red[2] + red[3] + bout[0];
        float o1 = red[4] + red[5] + red[6] + red[7] + bout[1];
        osh[0] = o0; osh[1] = o1;
        dout[(size_t)b * 360 + m * 60 + s * 2]     = o0;
        dout[(size_t)b * 360 + m * 60 + s * 2 + 1] = o1;
    }
    __syncthreads();
    float o0 = osh[0], o1 = osh[1];
    float g0 = loc[b * 12 + m * 2], g1 = loc[b * 12 + m * 2 + 1];
    next_state(n, b, t, o0, o1, g0, g1, (float)(OBS_ + s + 1),
               Wemb, bemb, Weff, featqp,
               &emb_gen[((size_t)s * N_ + n) * 32], A1f, ecA1b, small5, qp, A1s);
}

// ---------------------------------------------------------------------------
extern "C" void kernel_launch(void* const* d_in, const int* in_sizes, int n_in,
                              void* d_out_, int out_size, void* d_ws, size_t ws_size,
                              hipStream_t stream) {
    (void)in_sizes; (void)n_in; (void)out_size; (void)ws_size;
    const float* feat  = (const float*)d_in[0];
    const float* loc   = (const float*)d_in[1];
    const float* obs   = (const float*)d_in[2];
    const float* W_emb = (const float*)d_in[3];
    const float* b_emb = (const float*)d_in[4];
    const float* W_qkv = (const float*)d_in[5];
    const float* b_qkv = (const float*)d_in[6];
    const float* W_o   = (const float*)d_in[7];
    const float* b_o   = (const float*)d_in[8];
    const float* W_ff1 = (const float*)d_in[9];
    const float* b_ff1 = (const float*)d_in[10];
    const float* W_ff2 = (const float*)d_in[11];
    const float* b_ff2 = (const float*)d_in[12];
    const float* ln1_g = (const float*)d_in[13];
    const float* ln1_b = (const float*)d_in[14];
    const float* ln2_g = (const float*)d_in[15];
    const float* ln2_b = (const float*)d_in[16];
    const float* W_fus = (const float*)d_in[17];
    const float* b_fus = (const float*)d_in[18];
    const float* W_out = (const float*)d_in[19];
    const float* b_out = (const float*)d_in[20];
    float* dout = (float*)d_out_;

    float* ws = (float*)d_ws;
    float* Weff     = ws; ws += 513 * 256;
    float* featqp   = ws; ws += 256 * 256;
    float* featv    = ws; ws += 256 * 512;          // scratch, reused for Wvo_ex fp32
    float* featvO   = ws; ws += 256 * 512;
    float* feat_fus = ws; ws += 256 * 448;
    float* emb_obs  = ws; ws += OBS_ * B_ * 32;
    float* emb_gen  = ws; ws += HOR_ * N_ * 32;
    float* qp       = ws; ws += (size_t)N_ * 256;
    float* A1f      = ws; ws += (size_t)N_ * 64;
    float* small5   = ws; ws += (size_t)N_ * 8;
    float* aF       = ws; ws += (size_t)N_ * 512;
    float* ffB      = ws; ws += (size_t)N_ * 512;
    float* h1f      = ws; ws += (size_t)N_ * 512;
    float* fusv     = ws; ws += (size_t)N_ * 448;
    bf16* WovCat = (bf16*)ws; ws += (320 * 512) / 2;
    bf16* Wff1b  = (bf16*)ws; ws += (512 * 2048) / 2;
    bf16* Wff2b  = (bf16*)ws; ws += (2048 * 512) / 2;
    bf16* Wfusb  = (bf16*)ws; ws += (544 * 448) / 2;
    bf16* ecA1b  = (bf16*)ws; ws += ((size_t)N_ * 288) / 2;
    bf16* h1b    = (bf16*)ws; ws += ((size_t)N_ * 512) / 2;
    bf16* f1b    = (bf16*)ws; ws += ((size_t)N_ * 2048) / 2;
    bf16* h2p    = (bf16*)ws; ws += ((size_t)N_ * 544) / 2;

    // ---- prologue (once per launch) ----
    emb_obs_k<<<dim3(640), dim3(256), 0, stream>>>(obs, W_emb, b_emb, emb_obs);
    weff_k<<<dim3(513), dim3(256), 0, stream>>>(W_qkv, b_qkv, Weff);
    // featqp = feat @ Weff[64:512] + bias_qp(=Weff row 512)
    gemm_k<<<dim3(4, 4), dim3(256), 0, stream>>>(feat, 448, Weff + 64 * 256, 256,
        featqp, nullptr, 256, 448, Weff + 512 * 256);
    wov_k<<<dim3(256), dim3(256), 0, stream>>>(W_qkv, W_o, WovCat);
    // featv = feat @ Wv[64:512] + b_v
    gemm_k<<<dim3(8, 4), dim3(256), 0, stream>>>(feat, 448, W_qkv + 64 * 1536 + 1024, 1536,
        featv, nullptr, 512, 448, b_qkv + 1024);
    // featvO = featv @ W_o + b_o
    gemm_k<<<dim3(8, 4), dim3(256), 0, stream>>>(featv, 512, W_o, 512,
        featvO, nullptr, 512, 512, b_o);
    // Wvo_ex = Wv[extras rows] @ W_o -> WovCat rows 256..319 (bf16)
    gemm_k<<<dim3(8, 1), dim3(256), 0, stream>>>(W_qkv + 32 * 1536 + 1024, 1536, W_o, 512,
        featv, WovCat + 256 * 512, 512, 512, nullptr);
    // feat_fus = feat @ W_fus[519:967] + b_fus
    gemm_k<<<dim3(7, 4), dim3(256), 0, stream>>>(feat, 448, W_fus + 519 * 448, 448,
        feat_fus, nullptr, 448, 448, b_fus);
    convpad_k<<<dim3(4096), dim3(256), 0, stream>>>(W_ff1, Wff1b, 512, 2048, 512);
    convpad_k<<<dim3(4096), dim3(256), 0, stream>>>(W_ff2, Wff2b, 2048, 512, 2048);
    convpad_k<<<dim3(952),  dim3(256), 0, stream>>>(W_fus, Wfusb, 544, 448, 519);
    init_k<<<dim3(N_), dim3(256), 0, stream>>>(obs, emb_obs, loc, Weff, featqp,
        A1f, ecA1b, small5, qp);

    // ---- 30 sequential decode steps ----
    for (int s = 0; s < HOR_; s++) {
        attn_k<<<dim3(N_), dim3(256), 0, stream>>>(qp, emb_obs, emb_gen, ecA1b, OBS_ + s);
        // a = [ec|extras] @ WovCat + featvO[b]
        mgemm_k<<<dim3(8, 24), dim3(256), 0, stream>>>(ecA1b, 288, WovCat, 512, 288,
            aF, nullptr, 512, nullptr, featvO, 512, 0);
        ln1_k<<<dim3(N_), dim3(256), 0, stream>>>(aF, A1f, feat, ln1_g, ln1_b, h1f, h1b);
        // f1 = relu(h1 @ W_ff1 + b_ff1)   (bf16 out only)
        mgemm_k<<<dim3(32, 24), dim3(256), 0, stream>>>(h1b, 512, Wff1b, 2048, 512,
            nullptr, f1b, 2048, b_ff1, nullptr, 0, 1);
        // ff = f1 @ W_ff2 + b_ff2
        mgemm_k<<<dim3(8, 24), dim3(256), 0, stream>>>(f1b, 2048, Wff2b, 512, 2048,
            ffB, nullptr, 512, b_ff2, nullptr, 0, 0);
        ln2_k<<<dim3(N_), dim3(256), 0, stream>>>(h1f, ffB, ln2_g, ln2_b, small5, h2p);
        // fusv = h2p @ W_fus[0:519] + feat_fus[b]
        mgemm_k<<<dim3(7, 24), dim3(256), 0, stream>>>(h2p, 544, Wfusb, 448, 544,
            fusv, nullptr, 448, nullptr, feat_fus, 448, 0);
        finish_k<<<dim3(N_), dim3(256), 0, stream>>>(fusv, W_out, b_out, W_emb, b_emb,
            loc, Weff, featqp, dout, emb_gen, A1f, ecA1b, small5, qp, s);
    }
}